// Round 9
// baseline (626.295 us; speedup 1.0000x reference)
//
#include <hip/hip_runtime.h>
#include <hip/hip_bf16.h>

#define BATCH 4
#define NPTS  4096
#define NPTS2 4096
#define CIN   128
#define DIM   64
#define KNN   20
#define UPF   2
#define HPOS  64
#define HATT  256
#define MOUT  8192
#define EPSF  1e-5f
#define QPB   6            // queries per attn block
#define BPB   683          // ceil(4096/6) attn blocks per batch

// front kernel block ranges
#define FB_KNN   1024
#define FB_PKV   (FB_KNN + 256)
#define FB_PQ    (FB_PKV + 256)
#define FB_PACK  (FB_PQ + 128)

typedef _Float16 h16x8 __attribute__((ext_vector_type(8)));
typedef _Float16 h16x4 __attribute__((ext_vector_type(4)));
typedef _Float16 h16x2 __attribute__((ext_vector_type(2)));
typedef float    f32x4 __attribute__((ext_vector_type(4)));

__device__ inline float rdlane(float v, int src) {
  return __int_as_float(__builtin_amdgcn_readlane(__float_as_int(v), src));
}

// Bit-exact distance: explicit fma DAG -> identical value in every use site.
__device__ __forceinline__ float distf(float qn, float m2x, float m2y, float m2z,
                                       float x, float y, float z) {
  float s = __fmaf_rn(x, x, qn);
  s = __fmaf_rn(y, y, s);
  s = __fmaf_rn(z, z, s);
  s = __fmaf_rn(m2x, x, s);
  s = __fmaf_rn(m2y, y, s);
  s = __fmaf_rn(m2z, z, s);
  return s;
}

// ---------------------------------------------------------------------------
// front (unchanged from R15): fused {knn v5, proj_kv, proj_q, pack_weights}.
// ---------------------------------------------------------------------------
__global__ __launch_bounds__(256) void front(
    // knn
    const float* __restrict__ pos1, const float* __restrict__ pos2,
    int* __restrict__ idxout,
    // proj_kv
    const float* __restrict__ key_feat,
    const float* __restrict__ wk, const float* __restrict__ bk,
    const float* __restrict__ wv, const float* __restrict__ bv,
    float* __restrict__ k_t, float* __restrict__ v_t,
    // proj_q
    const float* __restrict__ query,
    const float* __restrict__ wq, const float* __restrict__ bq,
    float* __restrict__ q_t,
    // pack_weights
    const float* __restrict__ aw1, const float* __restrict__ awt,
    const float* __restrict__ pw2,
    const float* __restrict__ ag,  const float* __restrict__ av,
    const float* __restrict__ abt2, const float* __restrict__ am,
    const float* __restrict__ abt,
    const float* __restrict__ pg,  const float* __restrict__ pv,
    const float* __restrict__ pbt, const float* __restrict__ pm,
    const float* __restrict__ ab1, const float* __restrict__ pb1,
    const float* __restrict__ pw1,
    _Float16* __restrict__ aw1h, _Float16* __restrict__ awtP,
    _Float16* __restrict__ pw2h, float* __restrict__ abtX,
    float* __restrict__ ab1f, float* __restrict__ pw1f,
    float* __restrict__ pb1f) {
  __shared__ union {
    struct { float X[CIN][64]; float O[64][65]; } pj;
    struct { int cnt[16]; float dbuf[16][64]; int jbuf[16][64]; } kn;
  } smU;
  const int bid = blockIdx.x;
  const int t   = threadIdx.x;

  if (bid < FB_KNN) {
    // ---------------- knn v5 ----------------
    const int lane = t & 63;
    const int wv   = t >> 6;
    const int b    = bid >> 8;           // 256 blocks per batch
    const int nb   = (bid & 255) * 16;   // 16 queries per block
    const float* p2x = pos2 + (b * 3 + 0) * NPTS2;
    const float* p2y = pos2 + (b * 3 + 1) * NPTS2;
    const float* p2z = pos2 + (b * 3 + 2) * NPTS2;

    float qn[4], m2x[4], m2y[4], m2z[4];
#pragma unroll
    for (int qi = 0; qi < 4; ++qi) {
      int n = nb + wv * 4 + qi;
      float qx = pos1[(b * 3 + 0) * NPTS + n];
      float qy = pos1[(b * 3 + 1) * NPTS + n];
      float qz = pos1[(b * 3 + 2) * NPTS + n];
      qn[qi]  = qx * qx + qy * qy + qz * qz;
      m2x[qi] = -2.0f * qx; m2y[qi] = -2.0f * qy; m2z[qi] = -2.0f * qz;
    }

    float mymin[4] = {3.402823466e38f, 3.402823466e38f,
                      3.402823466e38f, 3.402823466e38f};
    f32x4 cx[4], cy[4], cz[4];
#pragma unroll 1
    for (int c = 0; c < 4; ++c) {
      int base = c * 1024 + lane * 4;
#pragma unroll
      for (int g = 0; g < 4; ++g) {
        cx[g] = *(const f32x4*)(p2x + base + g * 256);
        cy[g] = *(const f32x4*)(p2y + base + g * 256);
        cz[g] = *(const f32x4*)(p2z + base + g * 256);
      }
#pragma unroll
      for (int qi = 0; qi < 4; ++qi)
#pragma unroll
        for (int g = 0; g < 4; ++g)
#pragma unroll
          for (int e = 0; e < 4; ++e) {
            float d = distf(qn[qi], m2x[qi], m2y[qi], m2z[qi],
                            cx[g][e], cy[g][e], cz[g][e]);
            mymin[qi] = fminf(mymin[qi], d);
          }
    }

    float T0[4];
#pragma unroll
    for (int qi = 0; qi < 4; ++qi) {
      float v = mymin[qi];
#pragma unroll
      for (int k = 2; k <= 64; k <<= 1)
#pragma unroll
        for (int jj = k >> 1; jj >= 1; jj >>= 1) {
          float o = __shfl_xor(v, jj);
          bool up = ((lane & k) == 0);
          bool keepmin = (((lane & jj) == 0) == up);
          v = keepmin ? fminf(v, o) : fmaxf(v, o);
        }
      T0[qi] = rdlane(v, 19);
    }

    if (lane < 4) smU.kn.cnt[wv * 4 + lane] = 0;
    // per-wave private buffers; per-wave LDS in-order -> no barrier

#pragma unroll 1
    for (int c = 0; c < 4; ++c) {
      int base = c * 1024 + lane * 4;
#pragma unroll
      for (int g = 0; g < 4; ++g) {
        cx[g] = *(const f32x4*)(p2x + base + g * 256);
        cy[g] = *(const f32x4*)(p2y + base + g * 256);
        cz[g] = *(const f32x4*)(p2z + base + g * 256);
      }
#pragma unroll
      for (int qi = 0; qi < 4; ++qi) {
        const int qq = wv * 4 + qi;
#pragma unroll
        for (int g = 0; g < 4; ++g)
#pragma unroll
          for (int e = 0; e < 4; ++e) {
            float d = distf(qn[qi], m2x[qi], m2y[qi], m2z[qi],
                            cx[g][e], cy[g][e], cz[g][e]);
            if (d <= T0[qi]) {
              int slot = atomicAdd(&smU.kn.cnt[qq], 1);
              if (slot < 64) { smU.kn.dbuf[qq][slot] = d; smU.kn.jbuf[qq][slot] = base + g * 256 + e; }
            }
          }
      }
    }

#pragma unroll 1
    for (int qi = 0; qi < 4; ++qi) {
      const int qq = wv * 4 + qi;
      const int n  = nb + qq;
      const int cnt = smU.kn.cnt[qq];
      if (cnt <= 64) {
        float dk = (lane < cnt) ? smU.kn.dbuf[qq][lane] : 3.402823466e38f;
        int   jk = (lane < cnt) ? smU.kn.jbuf[qq][lane] : 0x7fffffff;
#pragma unroll
        for (int k = 2; k <= 64; k <<= 1) {
#pragma unroll
          for (int jj = k >> 1; jj >= 1; jj >>= 1) {
            float od = __shfl_xor(dk, jj);
            int   oj = __shfl_xor(jk, jj);
            bool mineSm = (dk < od) || (dk == od && jk < oj);
            bool up = ((lane & k) == 0);
            bool keepmin = (((lane & jj) == 0) == up);
            bool takeOther = (keepmin != mineSm);
            dk = takeOther ? od : dk;
            jk = takeOther ? oj : jk;
          }
        }
        if (lane < KNN) idxout[(b * NPTS + n) * KNN + lane] = jk;
      } else {
        float dl = 3.402823466e38f;
        int   il = 0;
        for (int j0 = 0; j0 < NPTS2; j0 += 64) {
          int j = j0 + lane;
          float d = distf(qn[qi], m2x[qi], m2y[qi], m2z[qi], p2x[j], p2y[j], p2z[j]);
          float T = rdlane(dl, 19);
          unsigned long long m = __ballot(d < T);
          while (m) {
            int src = __ffsll(m) - 1;
            m &= m - 1;
            float dd = rdlane(d, src);
            float T2 = rdlane(dl, 19);
            if (dd < T2) {
              int jj2 = j0 + src;
              float pd = __shfl_up(dl, 1);
              int   pi = __shfl_up(il, 1);
              if (dl > dd) {
                if (lane == 0 || pd <= dd) { dl = dd; il = jj2; }
                else                       { dl = pd; il = pi; }
              }
            }
          }
        }
        if (lane < KNN) idxout[(b * NPTS + n) * KNN + lane] = il;
      }
    }
  } else if (bid < FB_PKV) {
    // ---------------- proj_kv ----------------
    const int vb = bid - FB_KNN;
    const int b  = vb >> 6;
    const int n0 = (vb & 63) * 64;
    for (int l = t; l < CIN * 64; l += 256) {
      int c = l >> 6, i = l & 63;
      smU.pj.X[c][i] = key_feat[(b * CIN + c) * NPTS2 + n0 + i];
    }
    __syncthreads();
    const int n_l = t & 63;
    const int w   = __builtin_amdgcn_readfirstlane(t >> 6);
    float acck[16], accv[16];
#pragma unroll
    for (int i = 0; i < 16; ++i) { acck[i] = bk[w * 16 + i]; accv[i] = bv[w * 16 + i]; }
    for (int c = 0; c < CIN; ++c) {
      float xv = smU.pj.X[c][n_l];
#pragma unroll
      for (int i = 0; i < 16; ++i) {
        acck[i] += wk[(w * 16 + i) * CIN + c] * xv;
        accv[i] += wv[(w * 16 + i) * CIN + c] * xv;
      }
    }
#pragma unroll
    for (int i = 0; i < 16; ++i) smU.pj.O[n_l][w * 16 + i] = acck[i];
    __syncthreads();
    for (int l = t; l < 64 * 64; l += 256)
      k_t[(b * NPTS2 + n0 + (l >> 6)) * DIM + (l & 63)] = smU.pj.O[l >> 6][l & 63];
    __syncthreads();
#pragma unroll
    for (int i = 0; i < 16; ++i) smU.pj.O[n_l][w * 16 + i] = accv[i];
    __syncthreads();
    for (int l = t; l < 64 * 64; l += 256)
      v_t[(b * NPTS2 + n0 + (l >> 6)) * DIM + (l & 63)] = smU.pj.O[l >> 6][l & 63];
  } else if (bid < FB_PQ) {
    // ---------------- proj_q ----------------
    const int vb = bid - FB_PKV;
    const int b  = vb >> 6;
    const int n0 = (vb & 63) * 64;
    for (int l = t; l < CIN * 64; l += 256) {
      int c = l >> 6, i = l & 63;
      smU.pj.X[c][i] = query[(b * CIN + c) * NPTS + n0 + i];
    }
    __syncthreads();
    const int n_l = t & 63;
    const int w   = __builtin_amdgcn_readfirstlane(t >> 6);
    float acc[16];
#pragma unroll
    for (int i = 0; i < 16; ++i) acc[i] = bq[w * 16 + i];
    for (int c = 0; c < CIN; ++c) {
      float xv = smU.pj.X[c][n_l];
#pragma unroll
      for (int i = 0; i < 16; ++i) acc[i] += wq[(w * 16 + i) * CIN + c] * xv;
    }
#pragma unroll
    for (int i = 0; i < 16; ++i) smU.pj.O[n_l][w * 16 + i] = acc[i];
    __syncthreads();
    for (int l = t; l < 64 * 64; l += 256)
      q_t[(b * NPTS + n0 + (l >> 6)) * DIM + (l & 63)] = smU.pj.O[l >> 6][l & 63];
  } else {
    // ---------------- pack_weights ----------------
    int i = (bid - FB_PQ) * 256 + t;
    if (i < 16384) {
      int j = i >> 6;
      float inv = ag[j] / sqrtf(av[j] + EPSF);
      aw1h[i] = (_Float16)(aw1[i] * inv);
    }
    if (i < 32768) {
      int orr = i >> 8, j = i & 255;
      awtP[i] = (_Float16)awt[j * 128 + orr];
    }
    if (i < 4096) pw2h[i] = (_Float16)pw2[i];
    if (i < 256) {
      float inv = ag[i] / sqrtf(av[i] + EPSF);
      ab1f[i] = ab1[i] * inv + (abt2[i] - am[i] * inv);
    }
    if (i < 192) {
      int hc = i / 3;
      float inv = pg[hc] / sqrtf(pv[hc] + EPSF);
      pw1f[i] = pw1[i] * inv;
    }
    if (i < 128) abtX[i] = abt[i >> 1];
    if (i < 64) {
      float inv = pg[i] / sqrtf(pv[i] + EPSF);
      pb1f[i] = pb1[i] * inv + (pbt[i] - pm[i] * inv);
    }
  }
}

// ---------------------------------------------------------------------------
// attn_mfma (R20): R19 + out_proj fused into the epilogue.
//  out_proj was a strict consumer of agg (8MB write + 8MB read + dispatch +
//  launch gap). Each attn block produces exactly the 12 agg rows its out
//  slice needs; we (32KB f32) is L2-resident. Phase E now writes agg to LDS
//  (aggL, 3KB in dead AL1); new epilogue does the 128o x 12m x 64c GEMM with
//  IDENTICAL f32 math/order as out_proj (acc += w*a, c ascending, +be+query).
//  Verify: attn WRITE ~26MB (16 out + 9.6 prior); >>40MB = write-path regress.
// LDS map: hB [0,18432); h1B/aL0 [18432,36864); aL1 [36864,55296);
//          VGB [55296,72704); lgc [0,34816) post-D3; aggL [36864,39936) in E.
// ---------------------------------------------------------------------------
#define SM_HB    0
#define SM_H1B   18432
#define SM_AL0   18432
#define SM_AL1   36864
#define SM_VGB   55296
#define SM_LGC   0
#define SM_AGG   36864

__global__ __launch_bounds__(256, 2) void attn_mfma(
    const float* __restrict__ q_t, const float* __restrict__ k_t,
    const float* __restrict__ v_t, const int* __restrict__ idx,
    const float* __restrict__ pos1, const float* __restrict__ pos2,
    const float* __restrict__ pw1f, const float* __restrict__ pb1f,
    const _Float16* __restrict__ pw2h, const float* __restrict__ pb2,
    const _Float16* __restrict__ aw1h, const float* __restrict__ ab1f,
    const _Float16* __restrict__ awtP, const float* __restrict__ abtX,
    const float* __restrict__ we, const float* __restrict__ be,
    const float* __restrict__ query, float* __restrict__ out) {
  __shared__ __align__(16) char smem[72704];
  const int b  = blockIdx.x / BPB;
  const int n0 = (blockIdx.x - b * BPB) * QPB;
  const int t  = threadIdx.x;
  const int lane = t & 63;
  const int w  = t >> 6;        // wave id
  const int r  = lane & 15;     // tile lane index
  const int q4 = lane >> 4;     // quad
  const int c0 = t & 63;        // first col; second col = c0 + 64
  const int cgB = w;            // ch-group

  // Neighbor indices for both col-halves (L1-cached idx reads)
  int  jBh[2]; bool okh[2]; int nqh[2];
#pragma unroll
  for (int hl = 0; hl < 2; ++hl) {
    int colB = c0 + hl * 64;
    int pB = colB / 20;
    okh[hl] = (pB < QPB) && (n0 + pB < NPTS);
    nqh[hl] = okh[hl] ? (n0 + pB) : 0;
    jBh[hl] = okh[hl] ? idx[(b * NPTS + nqh[hl]) * KNN + (colB - pB * 20)] : 0;
  }

  // Prefetch half-0 q/k/v (hidden under Phase 1 + A); q-k folded at load.
  f32x4 qk4[4], vv4[4];
  {
    const float* qrow = q_t + ((size_t)(b * NPTS  + nqh[0])) * DIM + cgB * 16;
    const float* krow = k_t + ((size_t)(b * NPTS2 + jBh[0])) * DIM + cgB * 16;
    const float* vrow = v_t + ((size_t)(b * NPTS2 + jBh[0])) * DIM + cgB * 16;
#pragma unroll
    for (int u = 0; u < 4; ++u) {
      f32x4 qv = *(const f32x4*)(qrow + u * 4);
      f32x4 kv = *(const f32x4*)(krow + u * 4);
      qk4[u] = qv - kv;
      vv4[u] = *(const f32x4*)(vrow + u * 4);
    }
  }

  // Phase 1: pos-MLP hidden -> h1B f16 [col][hc] stride 72 (h1B arena)
#pragma unroll
  for (int hl = 0; hl < 2; ++hl) {
    int colB = c0 + hl * 64;
    float p0 = 0.f, p1 = 0.f, p2 = 0.f;
    if (okh[hl]) {
      p0 = pos1[(b * 3 + 0) * NPTS + nqh[hl]] - pos2[(b * 3 + 0) * NPTS2 + jBh[hl]];
      p1 = pos1[(b * 3 + 1) * NPTS + nqh[hl]] - pos2[(b * 3 + 1) * NPTS2 + jBh[hl]];
      p2 = pos1[(b * 3 + 2) * NPTS + nqh[hl]] - pos2[(b * 3 + 2) * NPTS2 + jBh[hl]];
    }
#pragma unroll
    for (int hf = 0; hf < 2; ++hf) {
      h16x8 pk;
#pragma unroll
      for (int ii = 0; ii < 8; ++ii) {
        int hc = cgB * 16 + hf * 8 + ii;
        float v0 = pb1f[hc] + pw1f[hc*3] * p0 + pw1f[hc*3+1] * p1 + pw1f[hc*3+2] * p2;
        v0 = fmaxf(v0, 0.f);
        if (!okh[hl]) v0 = 0.f;
        pk[ii] = (_Float16)v0;
      }
      *(h16x8*)(smem + SM_H1B + ((colB * 72 + cgB * 16 + hf * 8) * 2)) = pk;
    }
  }
  __syncthreads();   // bar 1: h1B cross-wave for A

  // Phase A: GEMM0 pe = pw2 @ h1 (+pb2) -> peL f16 [col][o] stride 72 (hB)
  {
    f32x4 acc[8];
#pragma unroll
    for (int nt = 0; nt < 8; ++nt) acc[nt] = (f32x4){0.f, 0.f, 0.f, 0.f};
#pragma unroll
    for (int ks = 0; ks < 2; ++ks) {
      h16x8 a0 = *(const h16x8*)&pw2h[(w * 16 + r) * 64 + ks * 32 + q4 * 8];
#pragma unroll
      for (int nt = 0; nt < 8; ++nt) {
        h16x8 bv = *(h16x8*)(smem + SM_H1B + ((nt * 16 + r) * 72 + ks * 32 + q4 * 8) * 2);
        acc[nt] = __builtin_amdgcn_mfma_f32_16x16x32_f16(a0, bv, acc[nt], 0, 0, 0);
      }
    }
    int o0 = w * 16 + q4 * 4;
    f32x4 pbv = *(const f32x4*)&pb2[o0];
#pragma unroll
    for (int nt = 0; nt < 8; ++nt) {
      f32x4 vv = acc[nt] + pbv;
      h16x4 pk = {(_Float16)vv[0], (_Float16)vv[1], (_Float16)vv[2], (_Float16)vv[3]};
      *(h16x4*)(smem + SM_HB + ((nt * 16 + r) * 72 + o0) * 2) = pk;
    }
  }
  // NO barrier: wave w wrote peL ch [16w,16w+16) for ALL 128 cols; B's thread
  // (cols {c0, c0+64}, cgB=w) reads only that range. Per-wave LDS in-order.

  // Phase B: h = (q-k)+pe IN PLACE over peL (hB); vg -> vgB stride 68.
#pragma unroll 1
  for (int hl = 0; hl < 2; ++hl) {
    int colB = c0 + hl * 64;
    if (hl == 1) {
      const float* qrow = q_t + ((size_t)(b * NPTS  + nqh[1])) * DIM + cgB * 16;
      const float* krow = k_t + ((size_t)(b * NPTS2 + jBh[1])) * DIM + cgB * 16;
      const float* vrow = v_t + ((size_t)(b * NPTS2 + jBh[1])) * DIM + cgB * 16;
#pragma unroll
      for (int u = 0; u < 4; ++u) {
        f32x4 qv = *(const f32x4*)(qrow + u * 4);
        f32x4 kv = *(const f32x4*)(krow + u * 4);
        qk4[u] = qv - kv;
        vv4[u] = *(const f32x4*)(vrow + u * 4);
      }
    }
    h16x8 pe8[2];
#pragma unroll
    for (int hf = 0; hf < 2; ++hf)
      pe8[hf] = *(h16x8*)(smem + SM_HB + (colB * 72 + cgB * 16 + hf * 8) * 2);
    h16x8 hp8[2];
#pragma unroll
    for (int u = 0; u < 4; ++u) {
      int hf = u >> 1, e0 = (u & 1) * 4;
      f32x4 pe = {(float)pe8[hf][e0],     (float)pe8[hf][e0 + 1],
                  (float)pe8[hf][e0 + 2], (float)pe8[hf][e0 + 3]};
      f32x4 hv = qk4[u] + pe;
      f32x4 gv = vv4[u] + pe;
      if (!okh[hl]) { hv = (f32x4){0.f,0.f,0.f,0.f}; gv = hv; }
      hp8[hf][e0]     = (_Float16)hv[0];
      hp8[hf][e0 + 1] = (_Float16)hv[1];
      hp8[hf][e0 + 2] = (_Float16)hv[2];
      hp8[hf][e0 + 3] = (_Float16)hv[3];
      h16x4 gp = {(_Float16)gv[0], (_Float16)gv[1], (_Float16)gv[2], (_Float16)gv[3]};
      *(h16x4*)(smem + SM_VGB + (colB * 68 + cgB * 16 + u * 4) * 2) = gp;
    }
#pragma unroll
    for (int hf = 0; hf < 2; ++hf)
      *(h16x8*)(smem + SM_HB + (colB * 72 + cgB * 16 + hf * 8) * 2) = hp8[hf];
  }
  __syncthreads();   // bar 2: hB cross-wave for C; h1B dead -> aL0 reuse

  // Phases C+D over four j-quarters; aL double-buffered (AL0/AL1), hB
  // persistent. One barrier per quarter: D(q) || C(q+1) overlap.
  f32x4 accD[2][8];
#pragma unroll
  for (int h = 0; h < 2; ++h)
#pragma unroll
    for (int nt = 0; nt < 8; ++nt) accD[h][nt] = (f32x4){0.f, 0.f, 0.f, 0.f};

#define C_QUARTER(quar, albase)                                                \
  {                                                                            \
    int mt = (quar) * 4 + w;                                                   \
    f32x4 acc[8];                                                              \
    _Pragma("unroll")                                                          \
    for (int nt = 0; nt < 8; ++nt) acc[nt] = (f32x4){0.f, 0.f, 0.f, 0.f};      \
    _Pragma("unroll")                                                          \
    for (int ks = 0; ks < 2; ++ks) {                                           \
      h16x8 af = *(const h16x8*)&aw1h[(mt * 16 + r) * 64 + ks * 32 + q4 * 8];  \
      h16x8 bsv[8];                                                            \
      _Pragma("unroll")                                                        \
      for (int nt = 0; nt < 8; ++nt)                                           \
        bsv[nt] = *(h16x8*)(smem + SM_HB + ((nt * 16 + r) * 72 + ks * 32 + q4 * 8) * 2); \
      _Pragma("unroll")                                                        \
      for (int nt = 0; nt < 8; ++nt)                                           \
        acc[nt] = __builtin_amdgcn_mfma_f32_16x16x32_f16(af, bsv[nt], acc[nt], 0, 0, 0); \
    }                                                                          \
    int j0  = mt * 16 + q4 * 4;                                                \
    int jq0 = j0 - (quar) * 64;                                                \
    f32x4 b1 = *(const f32x4*)&ab1f[j0];                                       \
    _Pragma("unroll")                                                          \
    for (int nt = 0; nt < 8; ++nt) {                                           \
      int col = nt * 16 + r;                                                   \
      float v0 = fmaxf(acc[nt][0] + b1[0], 0.f);                               \
      float v1 = fmaxf(acc[nt][1] + b1[1], 0.f);                               \
      float v2 = fmaxf(acc[nt][2] + b1[2], 0.f);                               \
      float v3 = fmaxf(acc[nt][3] + b1[3], 0.f);                               \
      h16x4 pk = {(_Float16)v0, (_Float16)v1, (_Float16)v2, (_Float16)v3};     \
      *(h16x4*)(smem + (albase) + (col * 72 + jq0) * 2) = pk;                  \
    }                                                                          \
  }

#define D_QUARTER(quar, albase)                                                \
  {                                                                            \
    _Pragma("unroll")                                                          \
    for (int ks2 = 0; ks2 < 2; ++ks2) {                                        \
      h16x8 bsv[8];                                                            \
      _Pragma("unroll")                                                        \
      for (int nt = 0; nt < 8; ++nt)                                           \
        bsv[nt] = *(h16x8*)(smem + (albase) + ((nt * 16 + r) * 72 + ks2 * 32 + q4 * 8) * 2); \
      int ksg = (quar) * 2 + ks2;                                              \
      _Pragma("unroll")                                                        \
      for (int h = 0; h < 2; ++h) {                                            \
        int mt2 = w * 2 + h;                                                   \
        h16x8 af = *(const h16x8*)&awtP[(mt2 * 16 + r) * 256 + ksg * 32 + q4 * 8]; \
        _Pragma("unroll")                                                      \
        for (int nt = 0; nt < 8; ++nt)                                         \
          accD[h][nt] = __builtin_amdgcn_mfma_f32_16x16x32_f16(af, bsv[nt], accD[h][nt], 0, 0, 0); \
      }                                                                        \
    }                                                                          \
  }

  C_QUARTER(0, SM_AL0)
  __syncthreads();   // bar 3: C0 visible for D0
  D_QUARTER(0, SM_AL0)
  C_QUARTER(1, SM_AL1)
  __syncthreads();   // bar 4: C1 visible; D0's AL0 reads done pre-C2
  D_QUARTER(1, SM_AL1)
  C_QUARTER(2, SM_AL0)
  __syncthreads();   // bar 5: C2 visible; D1's AL1 reads done pre-C3
  D_QUARTER(2, SM_AL0)
  C_QUARTER(3, SM_AL1)
  __syncthreads();   // bar 6: C3 visible; D2's AL0 reads done; hB reads done
  D_QUARTER(3, SM_AL1)

  // lgc write: [0,34816) overlays hB+aL0 -- both quiesced by bar 6; D3
  // concurrently reads only AL1 [36864,55296) -> disjoint, no barrier needed.
  {
#pragma unroll
    for (int h = 0; h < 2; ++h) {
      int orr0 = (w * 2 + h) * 16 + q4 * 4;
      f32x4 ab = *(const f32x4*)&abtX[orr0];
#pragma unroll
      for (int nt = 0; nt < 8; ++nt) {
        int col = nt * 16 + r;
        if (col < QPB * KNN) {
          f32x4 vv = accD[h][nt] + ab;
          h16x4 pk = {(_Float16)vv[0], (_Float16)vv[1], (_Float16)vv[2], (_Float16)vv[3]};
          *(h16x4*)(smem + SM_LGC + (col * 136 + orr0) * 2) = pk;
        }
      }
    }
  }
  __syncthreads();   // bar 7: lgc cross-wave for E; AL1 dead -> aggL reuse

  // Phase E: softmax+aggregate -> aggL[ml][li] f32 in LDS (ml = p*2+half).
#pragma unroll 1
  for (int it = 0; it < 2; ++it) {
    int p  = (t >> 6) + it * 4;
    int li = t & 63;
    if (p < QPB && n0 + p < NPTS) {
      h16x2 Lp[KNN];
      float G[KNN];
#pragma unroll
      for (int kk = 0; kk < KNN; ++kk) {
        Lp[kk] = *(h16x2*)(smem + SM_LGC + ((p * 20 + kk) * 136 + li * 2) * 2);
        G[kk]  = (float)*(_Float16*)(smem + SM_VGB + ((p * 20 + kk) * 68 + li) * 2);
      }
#pragma unroll
      for (int half = 0; half < 2; ++half) {
        float mx = (float)Lp[0][half];
#pragma unroll
        for (int kk = 1; kk < KNN; ++kk) mx = fmaxf(mx, (float)Lp[kk][half]);
        float s = 0.f, a = 0.f;
#pragma unroll
        for (int kk = 0; kk < KNN; ++kk) {
          float e = __expf((float)Lp[kk][half] - mx);
          s += e;
          a += e * G[kk];
        }
        float rs = 1.0f / s;
        *(float*)(smem + SM_AGG + (((p * 2 + half) * 64 + li) * 4)) = a * rs;
      }
    }
  }
  __syncthreads();   // bar 8: aggL complete for out-GEMM

  // Fused out_proj epilogue: out[o][m] = sum_c we[o][c]*aggL[m][c] + be[o]
  // + query[o][n] residual. Identical math/order to the old out_proj kernel.
  {
    const int o  = t & 127;
    const int mg = t >> 7;            // m-group: 0 -> ml 0..5, 1 -> ml 6..11
    const float* wrow = we + o * DIM;
    float acc[6];
#pragma unroll
    for (int mi = 0; mi < 6; ++mi) acc[mi] = 0.f;
    for (int c = 0; c < DIM; ++c) {
      float wv = wrow[c];
#pragma unroll
      for (int mi = 0; mi < 6; ++mi)
        acc[mi] += wv * *(const float*)(smem + SM_AGG + (((mg * 6 + mi) * 64 + c) * 4));
    }
    const float beo = be[o];
    const size_t orow = ((size_t)(b * CIN + o));
#pragma unroll
    for (int mi = 0; mi < 6; ++mi) {
      int ml = mg * 6 + mi;
      int p  = ml >> 1;
      if (n0 + p < NPTS) {
        out[orow * MOUT + (size_t)(n0 * 2 + ml)] =
            acc[mi] + beo + query[orow * NPTS + (size_t)(n0 + p)];
      }
    }
  }
#undef C_QUARTER
#undef D_QUARTER
}

// ---------------------------------------------------------------------------
extern "C" void kernel_launch(void* const* d_in, const int* in_sizes, int n_in,
                              void* d_out, int out_size, void* d_ws, size_t ws_size,
                              hipStream_t stream) {
  (void)in_sizes; (void)n_in; (void)out_size; (void)ws_size;
  const float* pos1     = (const float*)d_in[0];
  const float* query    = (const float*)d_in[1];
  const float* pos2     = (const float*)d_in[2];
  const float* key_feat = (const float*)d_in[3];
  const float* wq  = (const float*)d_in[4];
  const float* bq  = (const float*)d_in[5];
  const float* wk  = (const float*)d_in[6];
  const float* bk  = (const float*)d_in[7];
  const float* wv  = (const float*)d_in[8];
  const float* bv  = (const float*)d_in[9];
  const float* pw1 = (const float*)d_in[10];
  const float* pb1 = (const float*)d_in[11];
  const float* pg  = (const float*)d_in[12];
  const float* pbt = (const float*)d_in[13];
  const float* pm  = (const float*)d_in[14];
  const float* pv  = (const float*)d_in[15];
  const float* pw2 = (const float*)d_in[16];
  const float* pb2 = (const float*)d_in[17];
  const float* aw1 = (const float*)d_in[18];
  const float* ab1 = (const float*)d_in[19];
  const float* ag  = (const float*)d_in[20];
  const float* abt2= (const float*)d_in[21];
  const float* am  = (const float*)d_in[22];
  const float* av  = (const float*)d_in[23];
  const float* awt = (const float*)d_in[24];
  const float* abt = (const float*)d_in[25];
  const float* we  = (const float*)d_in[26];
  const float* be  = (const float*)d_in[27];

  float* ws   = (float*)d_ws;
  float* q_t  = ws;
  float* k_t  = q_t + BATCH * NPTS * DIM;
  float* v_t  = k_t + BATCH * NPTS2 * DIM;
  float* aggb = v_t + BATCH * NPTS2 * DIM;   // unused (fused); layout kept
  int*   idxb = (int*)(aggb + BATCH * MOUT * DIM);
  _Float16* aw1h = (_Float16*)(idxb + BATCH * NPTS * KNN);
  _Float16* awtP = aw1h + HATT * DIM;
  _Float16* pw2h = awtP + 128 * HATT;
  float* abtX    = (float*)(pw2h + DIM * HPOS);
  float* ab1f    = abtX + 128;
  float* pw1f    = ab1f + HATT;
  float* pb1f    = pw1f + HPOS * 3;

  front<<<FB_PACK, 256, 0, stream>>>(
      pos1, pos2, idxb,
      key_feat, wk, bk, wv, bv, k_t, v_t,
      query, wq, bq, q_t,
      aw1, awt, pw2, ag, av, abt2, am, abt,
      pg, pv, pbt, pm, ab1, pb1, pw1,
      aw1h, awtP, pw2h, abtX, ab1f, pw1f, pb1f);
  attn_mfma<<<BATCH * BPB, 256, 0, stream>>>(q_t, k_t, v_t, idxb, pos1, pos2,
      pw1f, pb1f, pw2h, pb2, aw1h, ab1f, awtP, abtX,
      we, be, query, (float*)d_out);
}

// Round 10
// 308.747 us; speedup vs baseline: 2.0285x; 2.0285x over previous
//
#include <hip/hip_runtime.h>
#include <hip/hip_bf16.h>

#define BATCH 4
#define NPTS  4096
#define NPTS2 4096
#define CIN   128
#define DIM   64
#define KNN   20
#define UPF   2
#define HPOS  64
#define HATT  256
#define MOUT  8192
#define EPSF  1e-5f
#define QPB   6            // queries per attn block
#define BPB   683          // ceil(4096/6) attn blocks per batch

// front kernel block ranges
#define FB_KNN   1024
#define FB_PKV   (FB_KNN + 256)
#define FB_PQ    (FB_PKV + 256)
#define FB_PACK  (FB_PQ + 128)

typedef _Float16 h16x8 __attribute__((ext_vector_type(8)));
typedef _Float16 h16x4 __attribute__((ext_vector_type(4)));
typedef _Float16 h16x2 __attribute__((ext_vector_type(2)));
typedef float    f32x4 __attribute__((ext_vector_type(4)));

__device__ inline float rdlane(float v, int src) {
  return __int_as_float(__builtin_amdgcn_readlane(__float_as_int(v), src));
}

// Bit-exact distance: explicit fma DAG -> identical value in every use site.
__device__ __forceinline__ float distf(float qn, float m2x, float m2y, float m2z,
                                       float x, float y, float z) {
  float s = __fmaf_rn(x, x, qn);
  s = __fmaf_rn(y, y, s);
  s = __fmaf_rn(z, z, s);
  s = __fmaf_rn(m2x, x, s);
  s = __fmaf_rn(m2y, y, s);
  s = __fmaf_rn(m2z, z, s);
  return s;
}

// ---------------------------------------------------------------------------
// front (unchanged from R15): fused {knn v5, proj_kv, proj_q, pack_weights}.
// ---------------------------------------------------------------------------
__global__ __launch_bounds__(256) void front(
    // knn
    const float* __restrict__ pos1, const float* __restrict__ pos2,
    int* __restrict__ idxout,
    // proj_kv
    const float* __restrict__ key_feat,
    const float* __restrict__ wk, const float* __restrict__ bk,
    const float* __restrict__ wv, const float* __restrict__ bv,
    float* __restrict__ k_t, float* __restrict__ v_t,
    // proj_q
    const float* __restrict__ query,
    const float* __restrict__ wq, const float* __restrict__ bq,
    float* __restrict__ q_t,
    // pack_weights
    const float* __restrict__ aw1, const float* __restrict__ awt,
    const float* __restrict__ pw2,
    const float* __restrict__ ag,  const float* __restrict__ av,
    const float* __restrict__ abt2, const float* __restrict__ am,
    const float* __restrict__ abt,
    const float* __restrict__ pg,  const float* __restrict__ pv,
    const float* __restrict__ pbt, const float* __restrict__ pm,
    const float* __restrict__ ab1, const float* __restrict__ pb1,
    const float* __restrict__ pw1,
    _Float16* __restrict__ aw1h, _Float16* __restrict__ awtP,
    _Float16* __restrict__ pw2h, float* __restrict__ abtX,
    float* __restrict__ ab1f, float* __restrict__ pw1f,
    float* __restrict__ pb1f) {
  __shared__ union {
    struct { float X[CIN][64]; float O[64][65]; } pj;
    struct { int cnt[16]; float dbuf[16][64]; int jbuf[16][64]; } kn;
  } smU;
  const int bid = blockIdx.x;
  const int t   = threadIdx.x;

  if (bid < FB_KNN) {
    // ---------------- knn v5 ----------------
    const int lane = t & 63;
    const int wv   = t >> 6;
    const int b    = bid >> 8;           // 256 blocks per batch
    const int nb   = (bid & 255) * 16;   // 16 queries per block
    const float* p2x = pos2 + (b * 3 + 0) * NPTS2;
    const float* p2y = pos2 + (b * 3 + 1) * NPTS2;
    const float* p2z = pos2 + (b * 3 + 2) * NPTS2;

    float qn[4], m2x[4], m2y[4], m2z[4];
#pragma unroll
    for (int qi = 0; qi < 4; ++qi) {
      int n = nb + wv * 4 + qi;
      float qx = pos1[(b * 3 + 0) * NPTS + n];
      float qy = pos1[(b * 3 + 1) * NPTS + n];
      float qz = pos1[(b * 3 + 2) * NPTS + n];
      qn[qi]  = qx * qx + qy * qy + qz * qz;
      m2x[qi] = -2.0f * qx; m2y[qi] = -2.0f * qy; m2z[qi] = -2.0f * qz;
    }

    float mymin[4] = {3.402823466e38f, 3.402823466e38f,
                      3.402823466e38f, 3.402823466e38f};
    f32x4 cx[4], cy[4], cz[4];
#pragma unroll 1
    for (int c = 0; c < 4; ++c) {
      int base = c * 1024 + lane * 4;
#pragma unroll
      for (int g = 0; g < 4; ++g) {
        cx[g] = *(const f32x4*)(p2x + base + g * 256);
        cy[g] = *(const f32x4*)(p2y + base + g * 256);
        cz[g] = *(const f32x4*)(p2z + base + g * 256);
      }
#pragma unroll
      for (int qi = 0; qi < 4; ++qi)
#pragma unroll
        for (int g = 0; g < 4; ++g)
#pragma unroll
          for (int e = 0; e < 4; ++e) {
            float d = distf(qn[qi], m2x[qi], m2y[qi], m2z[qi],
                            cx[g][e], cy[g][e], cz[g][e]);
            mymin[qi] = fminf(mymin[qi], d);
          }
    }

    float T0[4];
#pragma unroll
    for (int qi = 0; qi < 4; ++qi) {
      float v = mymin[qi];
#pragma unroll
      for (int k = 2; k <= 64; k <<= 1)
#pragma unroll
        for (int jj = k >> 1; jj >= 1; jj >>= 1) {
          float o = __shfl_xor(v, jj);
          bool up = ((lane & k) == 0);
          bool keepmin = (((lane & jj) == 0) == up);
          v = keepmin ? fminf(v, o) : fmaxf(v, o);
        }
      T0[qi] = rdlane(v, 19);
    }

    if (lane < 4) smU.kn.cnt[wv * 4 + lane] = 0;
    // per-wave private buffers; per-wave LDS in-order -> no barrier

#pragma unroll 1
    for (int c = 0; c < 4; ++c) {
      int base = c * 1024 + lane * 4;
#pragma unroll
      for (int g = 0; g < 4; ++g) {
        cx[g] = *(const f32x4*)(p2x + base + g * 256);
        cy[g] = *(const f32x4*)(p2y + base + g * 256);
        cz[g] = *(const f32x4*)(p2z + base + g * 256);
      }
#pragma unroll
      for (int qi = 0; qi < 4; ++qi) {
        const int qq = wv * 4 + qi;
#pragma unroll
        for (int g = 0; g < 4; ++g)
#pragma unroll
          for (int e = 0; e < 4; ++e) {
            float d = distf(qn[qi], m2x[qi], m2y[qi], m2z[qi],
                            cx[g][e], cy[g][e], cz[g][e]);
            if (d <= T0[qi]) {
              int slot = atomicAdd(&smU.kn.cnt[qq], 1);
              if (slot < 64) { smU.kn.dbuf[qq][slot] = d; smU.kn.jbuf[qq][slot] = base + g * 256 + e; }
            }
          }
      }
    }

#pragma unroll 1
    for (int qi = 0; qi < 4; ++qi) {
      const int qq = wv * 4 + qi;
      const int n  = nb + qq;
      const int cnt = smU.kn.cnt[qq];
      if (cnt <= 64) {
        float dk = (lane < cnt) ? smU.kn.dbuf[qq][lane] : 3.402823466e38f;
        int   jk = (lane < cnt) ? smU.kn.jbuf[qq][lane] : 0x7fffffff;
#pragma unroll
        for (int k = 2; k <= 64; k <<= 1) {
#pragma unroll
          for (int jj = k >> 1; jj >= 1; jj >>= 1) {
            float od = __shfl_xor(dk, jj);
            int   oj = __shfl_xor(jk, jj);
            bool mineSm = (dk < od) || (dk == od && jk < oj);
            bool up = ((lane & k) == 0);
            bool keepmin = (((lane & jj) == 0) == up);
            bool takeOther = (keepmin != mineSm);
            dk = takeOther ? od : dk;
            jk = takeOther ? oj : jk;
          }
        }
        if (lane < KNN) idxout[(b * NPTS + n) * KNN + lane] = jk;
      } else {
        float dl = 3.402823466e38f;
        int   il = 0;
        for (int j0 = 0; j0 < NPTS2; j0 += 64) {
          int j = j0 + lane;
          float d = distf(qn[qi], m2x[qi], m2y[qi], m2z[qi], p2x[j], p2y[j], p2z[j]);
          float T = rdlane(dl, 19);
          unsigned long long m = __ballot(d < T);
          while (m) {
            int src = __ffsll(m) - 1;
            m &= m - 1;
            float dd = rdlane(d, src);
            float T2 = rdlane(dl, 19);
            if (dd < T2) {
              int jj2 = j0 + src;
              float pd = __shfl_up(dl, 1);
              int   pi = __shfl_up(il, 1);
              if (dl > dd) {
                if (lane == 0 || pd <= dd) { dl = dd; il = jj2; }
                else                       { dl = pd; il = pi; }
              }
            }
          }
        }
        if (lane < KNN) idxout[(b * NPTS + n) * KNN + lane] = il;
      }
    }
  } else if (bid < FB_PKV) {
    // ---------------- proj_kv ----------------
    const int vb = bid - FB_KNN;
    const int b  = vb >> 6;
    const int n0 = (vb & 63) * 64;
    for (int l = t; l < CIN * 64; l += 256) {
      int c = l >> 6, i = l & 63;
      smU.pj.X[c][i] = key_feat[(b * CIN + c) * NPTS2 + n0 + i];
    }
    __syncthreads();
    const int n_l = t & 63;
    const int w   = __builtin_amdgcn_readfirstlane(t >> 6);
    float acck[16], accv[16];
#pragma unroll
    for (int i = 0; i < 16; ++i) { acck[i] = bk[w * 16 + i]; accv[i] = bv[w * 16 + i]; }
    for (int c = 0; c < CIN; ++c) {
      float xv = smU.pj.X[c][n_l];
#pragma unroll
      for (int i = 0; i < 16; ++i) {
        acck[i] += wk[(w * 16 + i) * CIN + c] * xv;
        accv[i] += wv[(w * 16 + i) * CIN + c] * xv;
      }
    }
#pragma unroll
    for (int i = 0; i < 16; ++i) smU.pj.O[n_l][w * 16 + i] = acck[i];
    __syncthreads();
    for (int l = t; l < 64 * 64; l += 256)
      k_t[(b * NPTS2 + n0 + (l >> 6)) * DIM + (l & 63)] = smU.pj.O[l >> 6][l & 63];
    __syncthreads();
#pragma unroll
    for (int i = 0; i < 16; ++i) smU.pj.O[n_l][w * 16 + i] = accv[i];
    __syncthreads();
    for (int l = t; l < 64 * 64; l += 256)
      v_t[(b * NPTS2 + n0 + (l >> 6)) * DIM + (l & 63)] = smU.pj.O[l >> 6][l & 63];
  } else if (bid < FB_PQ) {
    // ---------------- proj_q ----------------
    const int vb = bid - FB_PKV;
    const int b  = vb >> 6;
    const int n0 = (vb & 63) * 64;
    for (int l = t; l < CIN * 64; l += 256) {
      int c = l >> 6, i = l & 63;
      smU.pj.X[c][i] = query[(b * CIN + c) * NPTS + n0 + i];
    }
    __syncthreads();
    const int n_l = t & 63;
    const int w   = __builtin_amdgcn_readfirstlane(t >> 6);
    float acc[16];
#pragma unroll
    for (int i = 0; i < 16; ++i) acc[i] = bq[w * 16 + i];
    for (int c = 0; c < CIN; ++c) {
      float xv = smU.pj.X[c][n_l];
#pragma unroll
      for (int i = 0; i < 16; ++i) acc[i] += wq[(w * 16 + i) * CIN + c] * xv;
    }
#pragma unroll
    for (int i = 0; i < 16; ++i) smU.pj.O[n_l][w * 16 + i] = acc[i];
    __syncthreads();
    for (int l = t; l < 64 * 64; l += 256)
      q_t[(b * NPTS + n0 + (l >> 6)) * DIM + (l & 63)] = smU.pj.O[l >> 6][l & 63];
  } else {
    // ---------------- pack_weights ----------------
    int i = (bid - FB_PQ) * 256 + t;
    if (i < 16384) {
      int j = i >> 6;
      float inv = ag[j] / sqrtf(av[j] + EPSF);
      aw1h[i] = (_Float16)(aw1[i] * inv);
    }
    if (i < 32768) {
      int orr = i >> 8, j = i & 255;
      awtP[i] = (_Float16)awt[j * 128 + orr];
    }
    if (i < 4096) pw2h[i] = (_Float16)pw2[i];
    if (i < 256) {
      float inv = ag[i] / sqrtf(av[i] + EPSF);
      ab1f[i] = ab1[i] * inv + (abt2[i] - am[i] * inv);
    }
    if (i < 192) {
      int hc = i / 3;
      float inv = pg[hc] / sqrtf(pv[hc] + EPSF);
      pw1f[i] = pw1[i] * inv;
    }
    if (i < 128) abtX[i] = abt[i >> 1];
    if (i < 64) {
      float inv = pg[i] / sqrtf(pv[i] + EPSF);
      pb1f[i] = pb1[i] * inv + (pbt[i] - pm[i] * inv);
    }
  }
}

// ---------------------------------------------------------------------------
// attn_mfma (R21 == R19, the proven best): QPB=6 tile, aL double-buffer in
// LDS, D(q)||C(q+1) overlap, separate out_proj.
//  R20 post-mortem: fusing out_proj scattered the out/query/we accesses
//  (o on the lane -> 32KB-stride per-lane lines) -> 1.4GB traffic, +344us.
//  The dispatch+agg roundtrip (~15us) is far cheaper than uncoalesced
//  write amplification. R19 is the local optimum across all tested levers:
//  occupancy/FETCH/WRITE/barriers/setprio/swizzle/5-wave all null or worse.
// LDS map: hB [0,18432); h1B/aL0 [18432,36864); aL1 [36864,55296);
//          VGB [55296,72704); lgc [0,34816) post-D3.
// ---------------------------------------------------------------------------
#define SM_HB    0
#define SM_H1B   18432
#define SM_AL0   18432
#define SM_AL1   36864
#define SM_VGB   55296
#define SM_LGC   0

__global__ __launch_bounds__(256, 2) void attn_mfma(
    const float* __restrict__ q_t, const float* __restrict__ k_t,
    const float* __restrict__ v_t, const int* __restrict__ idx,
    const float* __restrict__ pos1, const float* __restrict__ pos2,
    const float* __restrict__ pw1f, const float* __restrict__ pb1f,
    const _Float16* __restrict__ pw2h, const float* __restrict__ pb2,
    const _Float16* __restrict__ aw1h, const float* __restrict__ ab1f,
    const _Float16* __restrict__ awtP, const float* __restrict__ abtX,
    float* __restrict__ agg) {
  __shared__ __align__(16) char smem[72704];
  const int b  = blockIdx.x / BPB;
  const int n0 = (blockIdx.x - b * BPB) * QPB;
  const int t  = threadIdx.x;
  const int lane = t & 63;
  const int w  = t >> 6;        // wave id
  const int r  = lane & 15;     // tile lane index
  const int q4 = lane >> 4;     // quad
  const int c0 = t & 63;        // first col; second col = c0 + 64
  const int cgB = w;            // ch-group

  // Neighbor indices for both col-halves (L1-cached idx reads)
  int  jBh[2]; bool okh[2]; int nqh[2];
#pragma unroll
  for (int hl = 0; hl < 2; ++hl) {
    int colB = c0 + hl * 64;
    int pB = colB / 20;
    okh[hl] = (pB < QPB) && (n0 + pB < NPTS);
    nqh[hl] = okh[hl] ? (n0 + pB) : 0;
    jBh[hl] = okh[hl] ? idx[(b * NPTS + nqh[hl]) * KNN + (colB - pB * 20)] : 0;
  }

  // Prefetch half-0 q/k/v (hidden under Phase 1 + A); q-k folded at load.
  f32x4 qk4[4], vv4[4];
  {
    const float* qrow = q_t + ((size_t)(b * NPTS  + nqh[0])) * DIM + cgB * 16;
    const float* krow = k_t + ((size_t)(b * NPTS2 + jBh[0])) * DIM + cgB * 16;
    const float* vrow = v_t + ((size_t)(b * NPTS2 + jBh[0])) * DIM + cgB * 16;
#pragma unroll
    for (int u = 0; u < 4; ++u) {
      f32x4 qv = *(const f32x4*)(qrow + u * 4);
      f32x4 kv = *(const f32x4*)(krow + u * 4);
      qk4[u] = qv - kv;
      vv4[u] = *(const f32x4*)(vrow + u * 4);
    }
  }

  // Phase 1: pos-MLP hidden -> h1B f16 [col][hc] stride 72 (h1B arena)
#pragma unroll
  for (int hl = 0; hl < 2; ++hl) {
    int colB = c0 + hl * 64;
    float p0 = 0.f, p1 = 0.f, p2 = 0.f;
    if (okh[hl]) {
      p0 = pos1[(b * 3 + 0) * NPTS + nqh[hl]] - pos2[(b * 3 + 0) * NPTS2 + jBh[hl]];
      p1 = pos1[(b * 3 + 1) * NPTS + nqh[hl]] - pos2[(b * 3 + 1) * NPTS2 + jBh[hl]];
      p2 = pos1[(b * 3 + 2) * NPTS + nqh[hl]] - pos2[(b * 3 + 2) * NPTS2 + jBh[hl]];
    }
#pragma unroll
    for (int hf = 0; hf < 2; ++hf) {
      h16x8 pk;
#pragma unroll
      for (int ii = 0; ii < 8; ++ii) {
        int hc = cgB * 16 + hf * 8 + ii;
        float v0 = pb1f[hc] + pw1f[hc*3] * p0 + pw1f[hc*3+1] * p1 + pw1f[hc*3+2] * p2;
        v0 = fmaxf(v0, 0.f);
        if (!okh[hl]) v0 = 0.f;
        pk[ii] = (_Float16)v0;
      }
      *(h16x8*)(smem + SM_H1B + ((colB * 72 + cgB * 16 + hf * 8) * 2)) = pk;
    }
  }
  __syncthreads();   // bar 1: h1B cross-wave for A

  // Phase A: GEMM0 pe = pw2 @ h1 (+pb2) -> peL f16 [col][o] stride 72 (hB)
  {
    f32x4 acc[8];
#pragma unroll
    for (int nt = 0; nt < 8; ++nt) acc[nt] = (f32x4){0.f, 0.f, 0.f, 0.f};
#pragma unroll
    for (int ks = 0; ks < 2; ++ks) {
      h16x8 a0 = *(const h16x8*)&pw2h[(w * 16 + r) * 64 + ks * 32 + q4 * 8];
#pragma unroll
      for (int nt = 0; nt < 8; ++nt) {
        h16x8 bv = *(h16x8*)(smem + SM_H1B + ((nt * 16 + r) * 72 + ks * 32 + q4 * 8) * 2);
        acc[nt] = __builtin_amdgcn_mfma_f32_16x16x32_f16(a0, bv, acc[nt], 0, 0, 0);
      }
    }
    int o0 = w * 16 + q4 * 4;
    f32x4 pbv = *(const f32x4*)&pb2[o0];
#pragma unroll
    for (int nt = 0; nt < 8; ++nt) {
      f32x4 vv = acc[nt] + pbv;
      h16x4 pk = {(_Float16)vv[0], (_Float16)vv[1], (_Float16)vv[2], (_Float16)vv[3]};
      *(h16x4*)(smem + SM_HB + ((nt * 16 + r) * 72 + o0) * 2) = pk;
    }
  }
  // NO barrier: wave w wrote peL ch [16w,16w+16) for ALL 128 cols; B's thread
  // (cols {c0, c0+64}, cgB=w) reads only that range. Per-wave LDS in-order.

  // Phase B: h = (q-k)+pe IN PLACE over peL (hB); vg -> vgB stride 68.
#pragma unroll 1
  for (int hl = 0; hl < 2; ++hl) {
    int colB = c0 + hl * 64;
    if (hl == 1) {
      const float* qrow = q_t + ((size_t)(b * NPTS  + nqh[1])) * DIM + cgB * 16;
      const float* krow = k_t + ((size_t)(b * NPTS2 + jBh[1])) * DIM + cgB * 16;
      const float* vrow = v_t + ((size_t)(b * NPTS2 + jBh[1])) * DIM + cgB * 16;
#pragma unroll
      for (int u = 0; u < 4; ++u) {
        f32x4 qv = *(const f32x4*)(qrow + u * 4);
        f32x4 kv = *(const f32x4*)(krow + u * 4);
        qk4[u] = qv - kv;
        vv4[u] = *(const f32x4*)(vrow + u * 4);
      }
    }
    h16x8 pe8[2];
#pragma unroll
    for (int hf = 0; hf < 2; ++hf)
      pe8[hf] = *(h16x8*)(smem + SM_HB + (colB * 72 + cgB * 16 + hf * 8) * 2);
    h16x8 hp8[2];
#pragma unroll
    for (int u = 0; u < 4; ++u) {
      int hf = u >> 1, e0 = (u & 1) * 4;
      f32x4 pe = {(float)pe8[hf][e0],     (float)pe8[hf][e0 + 1],
                  (float)pe8[hf][e0 + 2], (float)pe8[hf][e0 + 3]};
      f32x4 hv = qk4[u] + pe;
      f32x4 gv = vv4[u] + pe;
      if (!okh[hl]) { hv = (f32x4){0.f,0.f,0.f,0.f}; gv = hv; }
      hp8[hf][e0]     = (_Float16)hv[0];
      hp8[hf][e0 + 1] = (_Float16)hv[1];
      hp8[hf][e0 + 2] = (_Float16)hv[2];
      hp8[hf][e0 + 3] = (_Float16)hv[3];
      h16x4 gp = {(_Float16)gv[0], (_Float16)gv[1], (_Float16)gv[2], (_Float16)gv[3]};
      *(h16x4*)(smem + SM_VGB + (colB * 68 + cgB * 16 + u * 4) * 2) = gp;
    }
#pragma unroll
    for (int hf = 0; hf < 2; ++hf)
      *(h16x8*)(smem + SM_HB + (colB * 72 + cgB * 16 + hf * 8) * 2) = hp8[hf];
  }
  __syncthreads();   // bar 2: hB cross-wave for C; h1B dead -> aL0 reuse

  // Phases C+D over four j-quarters; aL double-buffered (AL0/AL1), hB
  // persistent. One barrier per quarter: D(q) || C(q+1) overlap.
  f32x4 accD[2][8];
#pragma unroll
  for (int h = 0; h < 2; ++h)
#pragma unroll
    for (int nt = 0; nt < 8; ++nt) accD[h][nt] = (f32x4){0.f, 0.f, 0.f, 0.f};

#define C_QUARTER(quar, albase)                                                \
  {                                                                            \
    int mt = (quar) * 4 + w;                                                   \
    f32x4 acc[8];                                                              \
    _Pragma("unroll")                                                          \
    for (int nt = 0; nt < 8; ++nt) acc[nt] = (f32x4){0.f, 0.f, 0.f, 0.f};      \
    _Pragma("unroll")                                                          \
    for (int ks = 0; ks < 2; ++ks) {                                           \
      h16x8 af = *(const h16x8*)&aw1h[(mt * 16 + r) * 64 + ks * 32 + q4 * 8];  \
      h16x8 bsv[8];                                                            \
      _Pragma("unroll")                                                        \
      for (int nt = 0; nt < 8; ++nt)                                           \
        bsv[nt] = *(h16x8*)(smem + SM_HB + ((nt * 16 + r) * 72 + ks * 32 + q4 * 8) * 2); \
      _Pragma("unroll")                                                        \
      for (int nt = 0; nt < 8; ++nt)                                           \
        acc[nt] = __builtin_amdgcn_mfma_f32_16x16x32_f16(af, bsv[nt], acc[nt], 0, 0, 0); \
    }                                                                          \
    int j0  = mt * 16 + q4 * 4;                                                \
    int jq0 = j0 - (quar) * 64;                                                \
    f32x4 b1 = *(const f32x4*)&ab1f[j0];                                       \
    _Pragma("unroll")                                                          \
    for (int nt = 0; nt < 8; ++nt) {                                           \
      int col = nt * 16 + r;                                                   \
      float v0 = fmaxf(acc[nt][0] + b1[0], 0.f);                               \
      float v1 = fmaxf(acc[nt][1] + b1[1], 0.f);                               \
      float v2 = fmaxf(acc[nt][2] + b1[2], 0.f);                               \
      float v3 = fmaxf(acc[nt][3] + b1[3], 0.f);                               \
      h16x4 pk = {(_Float16)v0, (_Float16)v1, (_Float16)v2, (_Float16)v3};     \
      *(h16x4*)(smem + (albase) + (col * 72 + jq0) * 2) = pk;                  \
    }                                                                          \
  }

#define D_QUARTER(quar, albase)                                                \
  {                                                                            \
    _Pragma("unroll")                                                          \
    for (int ks2 = 0; ks2 < 2; ++ks2) {                                        \
      h16x8 bsv[8];                                                            \
      _Pragma("unroll")                                                        \
      for (int nt = 0; nt < 8; ++nt)                                           \
        bsv[nt] = *(h16x8*)(smem + (albase) + ((nt * 16 + r) * 72 + ks2 * 32 + q4 * 8) * 2); \
      int ksg = (quar) * 2 + ks2;                                              \
      _Pragma("unroll")                                                        \
      for (int h = 0; h < 2; ++h) {                                            \
        int mt2 = w * 2 + h;                                                   \
        h16x8 af = *(const h16x8*)&awtP[(mt2 * 16 + r) * 256 + ksg * 32 + q4 * 8]; \
        _Pragma("unroll")                                                      \
        for (int nt = 0; nt < 8; ++nt)                                         \
          accD[h][nt] = __builtin_amdgcn_mfma_f32_16x16x32_f16(af, bsv[nt], accD[h][nt], 0, 0, 0); \
      }                                                                        \
    }                                                                          \
  }

  C_QUARTER(0, SM_AL0)
  __syncthreads();   // bar 3: C0 visible for D0
  D_QUARTER(0, SM_AL0)
  C_QUARTER(1, SM_AL1)
  __syncthreads();   // bar 4: C1 visible; D0's AL0 reads done pre-C2
  D_QUARTER(1, SM_AL1)
  C_QUARTER(2, SM_AL0)
  __syncthreads();   // bar 5: C2 visible; D1's AL1 reads done pre-C3
  D_QUARTER(2, SM_AL0)
  C_QUARTER(3, SM_AL1)
  __syncthreads();   // bar 6: C3 visible; D2's AL0 reads done; hB reads done
  D_QUARTER(3, SM_AL1)

  // lgc write: [0,34816) overlays hB+aL0 -- both quiesced by bar 6; D3
  // concurrently reads only AL1 [36864,55296) -> disjoint, no barrier needed.
  {
#pragma unroll
    for (int h = 0; h < 2; ++h) {
      int orr0 = (w * 2 + h) * 16 + q4 * 4;
      f32x4 ab = *(const f32x4*)&abtX[orr0];
#pragma unroll
      for (int nt = 0; nt < 8; ++nt) {
        int col = nt * 16 + r;
        if (col < QPB * KNN) {
          f32x4 vv = accD[h][nt] + ab;
          h16x4 pk = {(_Float16)vv[0], (_Float16)vv[1], (_Float16)vv[2], (_Float16)vv[3]};
          *(h16x4*)(smem + SM_LGC + (col * 136 + orr0) * 2) = pk;
        }
      }
    }
  }
  __syncthreads();   // bar 7: lgc cross-wave for E

  // Phase E: lane li owns output channel o=li for both upsample rows;
  // two passes cover p = 0..5 (waves 0..3 then 0..1).
#pragma unroll 1
  for (int it = 0; it < 2; ++it) {
    int p  = (t >> 6) + it * 4;
    int li = t & 63;
    if (p < QPB && n0 + p < NPTS) {
      h16x2 Lp[KNN];
      float G[KNN];
#pragma unroll
      for (int kk = 0; kk < KNN; ++kk) {
        Lp[kk] = *(h16x2*)(smem + SM_LGC + ((p * 20 + kk) * 136 + li * 2) * 2);
        G[kk]  = (float)*(_Float16*)(smem + SM_VGB + ((p * 20 + kk) * 68 + li) * 2);
      }
#pragma unroll
      for (int half = 0; half < 2; ++half) {
        float mx = (float)Lp[0][half];
#pragma unroll
        for (int kk = 1; kk < KNN; ++kk) mx = fmaxf(mx, (float)Lp[kk][half]);
        float s = 0.f, a = 0.f;
#pragma unroll
        for (int kk = 0; kk < KNN; ++kk) {
          float e = __expf((float)Lp[kk][half] - mx);
          s += e;
          a += e * G[kk];
        }
        float rs = 1.0f / s;
        agg[(((size_t)(b * NPTS + n0 + p)) * UPF + half) * DIM + li] = a * rs;
      }
    }
  }
#undef C_QUARTER
#undef D_QUARTER
}

// ---------------------------------------------------------------------------
// out_proj (restored, unchanged)
// ---------------------------------------------------------------------------
__global__ __launch_bounds__(256) void out_proj(const float* __restrict__ agg,
    const float* __restrict__ we, const float* __restrict__ be,
    const float* __restrict__ query, float* __restrict__ out) {
  __shared__ float A[64][65];
  const int b  = blockIdx.x >> 7;
  const int m0 = (blockIdx.x & 127) * 64;
  const int t  = threadIdx.x;
  for (int l = t; l < 64 * 64; l += 256) {
    int row = l >> 6, c = l & 63;
    A[row][c] = agg[(b * MOUT + m0 + row) * DIM + c];
  }
  __syncthreads();
  const int m_l = t & 63;
  const int w   = __builtin_amdgcn_readfirstlane(t >> 6);
  float acc[32];
#pragma unroll
  for (int i = 0; i < 32; ++i) acc[i] = 0.f;
  for (int c = 0; c < DIM; ++c) {
    float a = A[m_l][c];
#pragma unroll
    for (int i = 0; i < 32; ++i) acc[i] += we[(w * 32 + i) * DIM + c] * a;
  }
  const int m = m0 + m_l;
#pragma unroll
  for (int i = 0; i < 32; ++i) {
    int o = w * 32 + i;
    out[(b * CIN + o) * MOUT + m] = acc[i] + be[o] + query[(b * CIN + o) * NPTS + (m >> 1)];
  }
}

// ---------------------------------------------------------------------------
extern "C" void kernel_launch(void* const* d_in, const int* in_sizes, int n_in,
                              void* d_out, int out_size, void* d_ws, size_t ws_size,
                              hipStream_t stream) {
  (void)in_sizes; (void)n_in; (void)out_size; (void)ws_size;
  const float* pos1     = (const float*)d_in[0];
  const float* query    = (const float*)d_in[1];
  const float* pos2     = (const float*)d_in[2];
  const float* key_feat = (const float*)d_in[3];
  const float* wq  = (const float*)d_in[4];
  const float* bq  = (const float*)d_in[5];
  const float* wk  = (const float*)d_in[6];
  const float* bk  = (const float*)d_in[7];
  const float* wv  = (const float*)d_in[8];
  const float* bv  = (const float*)d_in[9];
  const float* pw1 = (const float*)d_in[10];
  const float* pb1 = (const float*)d_in[11];
  const float* pg  = (const float*)d_in[12];
  const float* pbt = (const float*)d_in[13];
  const float* pm  = (const float*)d_in[14];
  const float* pv  = (const float*)d_in[15];
  const float* pw2 = (const float*)d_in[16];
  const float* pb2 = (const float*)d_in[17];
  const float* aw1 = (const float*)d_in[18];
  const float* ab1 = (const float*)d_in[19];
  const float* ag  = (const float*)d_in[20];
  const float* abt2= (const float*)d_in[21];
  const float* am  = (const float*)d_in[22];
  const float* av  = (const float*)d_in[23];
  const float* awt = (const float*)d_in[24];
  const float* abt = (const float*)d_in[25];
  const float* we  = (const float*)d_in[26];
  const float* be  = (const float*)d_in[27];

  float* ws   = (float*)d_ws;
  float* q_t  = ws;
  float* k_t  = q_t + BATCH * NPTS * DIM;
  float* v_t  = k_t + BATCH * NPTS2 * DIM;
  float* aggb = v_t + BATCH * NPTS2 * DIM;
  int*   idxb = (int*)(aggb + BATCH * MOUT * DIM);
  _Float16* aw1h = (_Float16*)(idxb + BATCH * NPTS * KNN);
  _Float16* awtP = aw1h + HATT * DIM;
  _Float16* pw2h = awtP + 128 * HATT;
  float* abtX    = (float*)(pw2h + DIM * HPOS);
  float* ab1f    = abtX + 128;
  float* pw1f    = ab1f + HATT;
  float* pb1f    = pw1f + HPOS * 3;

  front<<<FB_PACK, 256, 0, stream>>>(
      pos1, pos2, idxb,
      key_feat, wk, bk, wv, bv, k_t, v_t,
      query, wq, bq, q_t,
      aw1, awt, pw2, ag, av, abt2, am, abt,
      pg, pv, pbt, pm, ab1, pb1, pw1,
      aw1h, awtP, pw2h, abtX, ab1f, pw1f, pb1f);
  attn_mfma<<<BATCH * BPB, 256, 0, stream>>>(q_t, k_t, v_t, idxb, pos1, pos2,
      pw1f, pb1f, pw2h, pb2, aw1h, ab1f, awtP, abtX, aggb);
  out_proj<<<BATCH * (MOUT / 64), 256, 0, stream>>>(aggb, we, be, query, (float*)d_out);
}